// Round 15
// baseline (149.993 us; speedup 1.0000x reference)
//
#include <hip/hip_runtime.h>

// EDeeperGCN: out[e] = relu(cat(x[src],x[dst]) @ W1 + b1) @ W2 + b2
// AB[n] = [x[n]@W1_top + b1 | x[n]@W1_bot]  (f16, in d_ws)
// out[e] = relu(A[src[e]] + B[dst[e]]) @ W2 + b2
//
// r14 post-mortem: L2-residency did NOT help -> the wall is per-unique-line
// request processing at the CU (~6 cyc per distinct 64B line; 8 lines/edge).
// r15: EXACT counting-sort of edges by src. A 16-edge wave then spans ~1-2
// distinct src rows, so the 4 A-gather instructions coalesce 16 lines -> ~2.
// Lines/edge 8 -> ~4.5. Edge kernel body is the proven r13/r14 one.
// Output is position-addressed by original edge id -> deterministic.
// MFMA map (proven): lane=16g+r; A row r, k=32st+8g+j; B col r;
// C/D col=lane&15, row=(lane>>4)*4+reg.

typedef _Float16 f16;
typedef _Float16 f16x8 __attribute__((ext_vector_type(8)));
typedef float    f32x4 __attribute__((ext_vector_type(4)));

#define HID  128
#define TWOH 256
#define OUTD 10

// ---------------- sort pass 0: zero histogram ----------------
__global__ __launch_bounds__(256) void zero_hist(int* __restrict__ h, int n) {
    const int i = blockIdx.x * 256 + threadIdx.x;
    if (i < n) h[i] = 0;
}

// ---------------- sort pass 1: histogram of src ----------------
__global__ __launch_bounds__(256) void hist_src(
    const int* __restrict__ ei, int n_edges, int* __restrict__ hist)
{
    const int e = blockIdx.x * 256 + threadIdx.x;
    if (e < n_edges) atomicAdd(&hist[ei[e]], 1);
}

// ---------------- sort pass 2: exclusive prefix sum (1 block) ----------------
__global__ __launch_bounds__(1024) void scan_hist(int* __restrict__ hist, int n)
{
    __shared__ int part[1024];
    const int t = threadIdx.x;
    const int base = t * 10;                 // 1024*10 >= 10000
    int v[10], s = 0;
#pragma unroll
    for (int i = 0; i < 10; ++i) {
        const int idx = base + i;
        v[i] = (idx < n) ? hist[idx] : 0;
        s += v[i];
    }
    part[t] = s;
    __syncthreads();
    for (int off = 1; off < 1024; off <<= 1) {
        const int x = (t >= off) ? part[t - off] : 0;
        __syncthreads();
        part[t] += x;
        __syncthreads();
    }
    int run = (t == 0) ? 0 : part[t - 1];
#pragma unroll
    for (int i = 0; i < 10; ++i) {
        const int idx = base + i;
        if (idx < n) { const int c = v[i]; hist[idx] = run; run += c; }
    }
}

// ---------------- sort pass 3: scatter into src-sorted order ----------------
// sorted[pos] = ((src<<16)|dst, original_e). Intra-run order nondeterministic
// but outputs are position-addressed by original e -> deterministic result.
__global__ __launch_bounds__(256) void scatter_src(
    const int* __restrict__ ei, int n_edges,
    int* __restrict__ offs, int2* __restrict__ sorted)
{
    const int e = blockIdx.x * 256 + threadIdx.x;
    if (e < n_edges) {
        const int src = ei[e];
        const int dst = ei[(long)n_edges + e];
        const int pos = atomicAdd(&offs[src], 1);
        sorted[pos] = make_int2((src << 16) | dst, e);
    }
}

// ---------------- Kernel 0: pack weight fragments ----------------
__global__ __launch_bounds__(256) void prep_weights(
    const float* __restrict__ W1,   // [256, 128]
    const float* __restrict__ W2,   // [128, 10]
    f16* __restrict__ W1P,          // 4096 slots x 8
    f16* __restrict__ W2P)          // 256 slots x 8
{
    const int slot = blockIdx.x * 256 + threadIdx.x;
    if (slot < 4096) {
        const int lane = slot & 63, i = slot >> 6;
        const int r = lane & 15, g = lane >> 4;
        const int T = i >> 2, st = i & 3;
        const int c = T * 16 + r;
        f16x8 v;
#pragma unroll
        for (int j = 0; j < 8; ++j) {
            const int k = st * 32 + g * 8 + j;
            const float w = (c < HID) ? W1[k * HID + c]
                                      : W1[(HID + k) * HID + (c - HID)];
            v[j] = (f16)w;
        }
        *(f16x8*)(W1P + (long)slot * 8) = v;
    } else if (slot < 4096 + 256) {
        const int s2 = slot - 4096;
        const int lane = s2 & 63, st = s2 >> 6;
        const int r = lane & 15, g = lane >> 4;
        f16x8 v;
#pragma unroll
        for (int j = 0; j < 8; ++j)
            v[j] = (r < OUTD) ? (f16)W2[(st * 32 + g * 8 + j) * OUTD + r] : (f16)0.f;
        *(f16x8*)(W2P + (long)s2 * 8) = v;
    }
}

// ---------------- Kernel 1: AB = x @ W1cat + [b1|0], f16 out, MFMA (r13-proven) ----------------
__global__ __launch_bounds__(256, 6) void node_AB(
    const float* __restrict__ x,    // [N, 128]
    const f16* __restrict__ W1P,
    const float* __restrict__ b1,   // [128]
    f16* __restrict__ AB,           // [N, 256]
    int n_nodes)
{
    const int t = threadIdx.x;
    const int lane = t & 63;
    const int r = lane & 15, g = lane >> 4;
    const int wv = t >> 6;
    const int n0 = (blockIdx.x >> 2) * 16;
    const int T = (blockIdx.x & 3) * 4 + wv;
    const int c = T * 16 + r;

    const int xrow = (n0 + r < n_nodes) ? (n0 + r) : (n_nodes - 1);
    float4 xl[4][2];
#pragma unroll
    for (int st = 0; st < 4; ++st) {
        const float* xp = x + (long)xrow * HID + st * 32 + g * 8;
        xl[st][0] = *(const float4*)xp;
        xl[st][1] = *(const float4*)(xp + 4);
    }

    f16x8 w1f[4];
#pragma unroll
    for (int st = 0; st < 4; ++st)
        w1f[st] = *(const f16x8*)(W1P + ((long)(T * 4 + st) * 64 + lane) * 8);
    const float bias = (c < HID) ? b1[c] : 0.f;

    f32x4 acc = {0, 0, 0, 0};
#pragma unroll
    for (int st = 0; st < 4; ++st) {
        f16x8 a;
        a[0] = (f16)xl[st][0].x; a[1] = (f16)xl[st][0].y;
        a[2] = (f16)xl[st][0].z; a[3] = (f16)xl[st][0].w;
        a[4] = (f16)xl[st][1].x; a[5] = (f16)xl[st][1].y;
        a[6] = (f16)xl[st][1].z; a[7] = (f16)xl[st][1].w;
        acc = __builtin_amdgcn_mfma_f32_16x16x32_f16(a, w1f[st], acc, 0, 0, 0);
    }

#pragma unroll
    for (int q = 0; q < 4; ++q) {
        const int node = n0 + g * 4 + q;
        if (node < n_nodes)
            AB[(long)node * TWOH + c] = (f16)(acc[q] + bias);
    }
}

// ---------------- Kernel 2: src-sorted edge gather + relu + [128x10] GEMM ----------------
// Block = 4 waves x 16 edges; 10000 blocks. A-gathers now hit ~1-2 distinct
// lines per instruction (src runs); B-gathers unchanged (16 lines).
__global__ __launch_bounds__(256, 6) void edge_mlp(
    const f16* __restrict__ AB,     // [N, 256]
    const int2* __restrict__ sorted,
    const f16* __restrict__ W2P,
    const float* __restrict__ b2,   // [10]
    float* __restrict__ out,        // [E, 10]
    int n_edges)
{
    const int t = threadIdx.x;
    const int lane = t & 63;
    const int r = lane & 15, g = lane >> 4;
    const int wv = t >> 6;

    const long slot0 = (long)blockIdx.x * 64 + wv * 16;
    if (slot0 >= n_edges) return;                   // wave-uniform
    const long sl = slot0 + r;
    const long slc = (sl < n_edges) ? sl : (n_edges - 1);
    const int2 se = sorted[slc];                    // coalesced
    const int sn = se.x >> 16;
    const int dn = se.x & 0xFFFF;

    // 8 line-perfect gathers (A-side coalesces across the sorted run)
    const f16* pa = AB + ((long)sn * TWOH + g * 8);
    const f16* pb = AB + ((long)dn * TWOH + HID + g * 8);
    f16x8 a0 = *(const f16x8*)pa;
    f16x8 a1 = *(const f16x8*)(pa + 32);
    f16x8 a2 = *(const f16x8*)(pa + 64);
    f16x8 a3 = *(const f16x8*)(pa + 96);
    f16x8 c0 = *(const f16x8*)pb;
    f16x8 c1 = *(const f16x8*)(pb + 32);
    f16x8 c2 = *(const f16x8*)(pb + 64);
    f16x8 c3 = *(const f16x8*)(pb + 96);

    // W2 B-fragment: 4 coalesced b128 loads (L2-hot, 4 KB total)
    f16x8 w2f[4];
#pragma unroll
    for (int st = 0; st < 4; ++st)
        w2f[st] = *(const f16x8*)(W2P + ((long)st * 64 + lane) * 8);
    const float bj = b2[(r < OUTD) ? r : 0];

    const f16x8 zt = {0, 0, 0, 0, 0, 0, 0, 0};
    f32x4 acc = {0, 0, 0, 0};
    f16x8 s;
    s = __builtin_elementwise_max(a0 + c0, zt);
    acc = __builtin_amdgcn_mfma_f32_16x16x32_f16(s, w2f[0], acc, 0, 0, 0);
    s = __builtin_elementwise_max(a1 + c1, zt);
    acc = __builtin_amdgcn_mfma_f32_16x16x32_f16(s, w2f[1], acc, 0, 0, 0);
    s = __builtin_elementwise_max(a2 + c2, zt);
    acc = __builtin_amdgcn_mfma_f32_16x16x32_f16(s, w2f[2], acc, 0, 0, 0);
    s = __builtin_elementwise_max(a3 + c3, zt);
    acc = __builtin_amdgcn_mfma_f32_16x16x32_f16(s, w2f[3], acc, 0, 0, 0);

    if (r < OUTD) {                                 // D: col r = output j
#pragma unroll
        for (int q = 0; q < 4; ++q) {
            const long s2i = slot0 + g * 4 + q;     // D row = edge slot
            if (s2i < n_edges) {
                const int eo = sorted[s2i].y;       // broadcast across r
                out[(long)eo * OUTD + r] = acc[q] + bj;
            }
        }
    }
}

extern "C" void kernel_launch(void* const* d_in, const int* in_sizes, int n_in,
                              void* d_out, int out_size, void* d_ws, size_t ws_size,
                              hipStream_t stream) {
    const float* x  = (const float*)d_in[0];
    const int*   ei = (const int*)d_in[1];
    const float* W1 = (const float*)d_in[2];
    const float* b1 = (const float*)d_in[3];
    const float* W2 = (const float*)d_in[4];
    const float* b2 = (const float*)d_in[5];
    float* out = (float*)d_out;

    const int n_nodes = in_sizes[0] / HID;          // 10000
    const int n_edges = in_sizes[1] / 2;            // 640000

    // ws layout: AB | W1P | W2P | hist | sorted  (~10.4 MB)
    f16*  AB     = (f16*)d_ws;                      // n_nodes*256 f16 = 5.12 MB
    f16*  W1P    = AB + (long)n_nodes * TWOH;       // 64 KB
    f16*  W2P    = W1P + 4096 * 8;                  // 4 KB
    int*  hist   = (int*)(W2P + 256 * 8);           // n_nodes ints
    int2* sorted = (int2*)(hist + ((n_nodes + 63) & ~63)); // n_edges int2

    zero_hist<<<(n_nodes + 255) / 256, 256, 0, stream>>>(hist, n_nodes);

    prep_weights<<<17, 256, 0, stream>>>(W1, W2, W1P, W2P);

    hist_src<<<(n_edges + 255) / 256, 256, 0, stream>>>(ei, n_edges, hist);

    scan_hist<<<1, 1024, 0, stream>>>(hist, n_nodes);

    scatter_src<<<(n_edges + 255) / 256, 256, 0, stream>>>(ei, n_edges, hist, sorted);

    node_AB<<<((n_nodes + 15) / 16) * 4, 256, 0, stream>>>(x, W1P, b1, AB, n_nodes);

    edge_mlp<<<(n_edges + 63) / 64, 256, 0, stream>>>(AB, sorted, W2P, b2, out, n_edges);
}

// Round 17
// 93.722 us; speedup vs baseline: 1.6004x; 1.6004x over previous
//
#include <hip/hip_runtime.h>

// EDeeperGCN: out[e] = relu(cat(x[src],x[dst]) @ W1 + b1) @ W2 + b2
// AB[n] = [x[n]@W1_top + b1 | x[n]@W1_bot]  (f16, in d_ws)
// out[e] = relu(A[src[e]] + B[dst[e]]) @ W2 + b2
//
// r14/r15 post-mortem: the edge-gather wall (~6 cyc per distinct 64B line/CU,
// invariant to occupancy, L2-residency, scheduling) fits a fixed per-CU L1
// miss-queue (MSHR) limit. r17 bypasses L1 with nontemporal loads on the
// gathers (gfx950 'nt' flag -> no L1 allocation). node_AB stages its
// block-shared x-tile in LDS. r16 fix: nontemporal builtins need
// ext_vector_type pointers, not HIP float4 structs.
// MFMA map (proven): lane=16g+r; A row r, k=32st+8g+j; B col r;
// C/D col=lane&15, row=(lane>>4)*4+reg.

typedef _Float16 f16;
typedef _Float16 f16x8 __attribute__((ext_vector_type(8)));
typedef float    f32x4 __attribute__((ext_vector_type(4)));

#define HID  128
#define TWOH 256
#define OUTD 10

// ---------------- Kernel 0: pack weight fragments ----------------
__global__ __launch_bounds__(256) void prep_weights(
    const float* __restrict__ W1,   // [256, 128]
    const float* __restrict__ W2,   // [128, 10]
    f16* __restrict__ W1P,          // 4096 slots x 8
    f16* __restrict__ W2P)          // 256 slots x 8
{
    const int slot = blockIdx.x * 256 + threadIdx.x;
    if (slot < 4096) {
        const int lane = slot & 63, i = slot >> 6;
        const int r = lane & 15, g = lane >> 4;
        const int T = i >> 2, st = i & 3;
        const int c = T * 16 + r;
        f16x8 v;
#pragma unroll
        for (int j = 0; j < 8; ++j) {
            const int k = st * 32 + g * 8 + j;
            const float w = (c < HID) ? W1[k * HID + c]
                                      : W1[(HID + k) * HID + (c - HID)];
            v[j] = (f16)w;
        }
        *(f16x8*)(W1P + (long)slot * 8) = v;
    } else if (slot < 4096 + 256) {
        const int s2 = slot - 4096;
        const int lane = s2 & 63, st = s2 >> 6;
        const int r = lane & 15, g = lane >> 4;
        f16x8 v;
#pragma unroll
        for (int j = 0; j < 8; ++j)
            v[j] = (r < OUTD) ? (f16)W2[(st * 32 + g * 8 + j) * OUTD + r] : (f16)0.f;
        *(f16x8*)(W2P + (long)s2 * 8) = v;
    }
}

// ---------------- Kernel 1: AB = x @ W1cat + [b1|0], f16 out, MFMA ----------------
// Block b: node tile b>>2 (16 nodes), col group b&3 (64 cols); wave = 16 cols.
// x-tile (8 KB, shared by all 4 waves) staged once in LDS, padded [16][132].
__global__ __launch_bounds__(256, 6) void node_AB(
    const float* __restrict__ x,    // [N, 128]
    const f16* __restrict__ W1P,
    const float* __restrict__ b1,   // [128]
    f16* __restrict__ AB,           // [N, 256]
    int n_nodes)
{
    __shared__ float xs[16][132];
    const int t = threadIdx.x;
    const int lane = t & 63;
    const int r = lane & 15, g = lane >> 4;
    const int wv = t >> 6;
    const int n0 = (blockIdx.x >> 2) * 16;
    const int T = (blockIdx.x & 3) * 4 + wv;
    const int c = T * 16 + r;

    // stage x-tile: 512 f32x4s, 2 per thread, coalesced, nontemporal
#pragma unroll
    for (int i = 0; i < 2; ++i) {
        const int idx = t + i * 256;              // f32x4 index
        const int row = idx >> 5, c4 = idx & 31;
        const int xr = (n0 + row < n_nodes) ? (n0 + row) : (n_nodes - 1);
        const f32x4 v = __builtin_nontemporal_load(
            (const f32x4*)(x + (long)xr * HID + c4 * 4));
        *(f32x4*)&xs[row][c4 * 4] = v;
    }
    __syncthreads();

    f16x8 w1f[4];
#pragma unroll
    for (int st = 0; st < 4; ++st)
        w1f[st] = *(const f16x8*)(W1P + ((long)(T * 4 + st) * 64 + lane) * 8);
    const float bias = (c < HID) ? b1[c] : 0.f;

    f32x4 acc = {0, 0, 0, 0};
#pragma unroll
    for (int st = 0; st < 4; ++st) {
        const f32x4 x0 = *(const f32x4*)&xs[r][st * 32 + g * 8];
        const f32x4 x1 = *(const f32x4*)&xs[r][st * 32 + g * 8 + 4];
        f16x8 a;
        a[0] = (f16)x0[0]; a[1] = (f16)x0[1]; a[2] = (f16)x0[2]; a[3] = (f16)x0[3];
        a[4] = (f16)x1[0]; a[5] = (f16)x1[1]; a[6] = (f16)x1[2]; a[7] = (f16)x1[3];
        acc = __builtin_amdgcn_mfma_f32_16x16x32_f16(a, w1f[st], acc, 0, 0, 0);
    }

#pragma unroll
    for (int q = 0; q < 4; ++q) {
        const int node = n0 + g * 4 + q;           // D row = node-within-tile
        if (node < n_nodes)
            AB[(long)node * TWOH + c] = (f16)(acc[q] + bias);
    }
}

// ---------------- Kernel 2: edge gather + relu + [128x10] GEMM, MFMA ----------------
// Block = 4 waves x 16 edges = 64 edges; 10000 blocks. 8 line-perfect gathers
// per wave, NONTEMPORAL (bypass L1 / its miss queue).
__global__ __launch_bounds__(256, 6) void edge_mlp(
    const f16* __restrict__ AB,     // [N, 256]
    const int* __restrict__ ei,     // [2, E]
    const f16* __restrict__ W2P,
    const float* __restrict__ b2,   // [10]
    float* __restrict__ out,        // [E, 10]
    int n_edges)
{
    const int t = threadIdx.x;
    const int lane = t & 63;
    const int r = lane & 15, g = lane >> 4;
    const int wv = t >> 6;

    const long eb = (long)blockIdx.x * 64 + wv * 16;
    const long e = eb + r;
    const long ec = (e < n_edges) ? e : (n_edges - 1);
    const int sn = ei[ec];                         // 4-way broadcast across g
    const int dn = ei[(long)n_edges + ec];

    // 8 line-perfect gathers, L1-bypassing
    const f16* pa = AB + ((long)sn * TWOH + g * 8);
    const f16* pb = AB + ((long)dn * TWOH + HID + g * 8);
    const f16x8 a0 = __builtin_nontemporal_load((const f16x8*)pa);
    const f16x8 a1 = __builtin_nontemporal_load((const f16x8*)(pa + 32));
    const f16x8 a2 = __builtin_nontemporal_load((const f16x8*)(pa + 64));
    const f16x8 a3 = __builtin_nontemporal_load((const f16x8*)(pa + 96));
    const f16x8 c0 = __builtin_nontemporal_load((const f16x8*)pb);
    const f16x8 c1 = __builtin_nontemporal_load((const f16x8*)(pb + 32));
    const f16x8 c2 = __builtin_nontemporal_load((const f16x8*)(pb + 64));
    const f16x8 c3 = __builtin_nontemporal_load((const f16x8*)(pb + 96));

    // W2 B-fragment: 4 coalesced b128 loads (reused -> normal cached loads)
    f16x8 w2f[4];
#pragma unroll
    for (int st = 0; st < 4; ++st)
        w2f[st] = *(const f16x8*)(W2P + ((long)st * 64 + lane) * 8);
    const float bj = b2[(r < OUTD) ? r : 0];

    const f16x8 zt = {0, 0, 0, 0, 0, 0, 0, 0};
    f32x4 acc = {0, 0, 0, 0};
    f16x8 s;
    s = __builtin_elementwise_max(a0 + c0, zt);
    acc = __builtin_amdgcn_mfma_f32_16x16x32_f16(s, w2f[0], acc, 0, 0, 0);
    s = __builtin_elementwise_max(a1 + c1, zt);
    acc = __builtin_amdgcn_mfma_f32_16x16x32_f16(s, w2f[1], acc, 0, 0, 0);
    s = __builtin_elementwise_max(a2 + c2, zt);
    acc = __builtin_amdgcn_mfma_f32_16x16x32_f16(s, w2f[2], acc, 0, 0, 0);
    s = __builtin_elementwise_max(a3 + c3, zt);
    acc = __builtin_amdgcn_mfma_f32_16x16x32_f16(s, w2f[3], acc, 0, 0, 0);

    if (r < OUTD) {                                // D: col r = output j
#pragma unroll
        for (int q = 0; q < 4; ++q) {
            const long ee = eb + g * 4 + q;        // D row = edge-within-tile
            if (ee < n_edges)
                out[ee * OUTD + r] = acc[q] + bj;
        }
    }
}

extern "C" void kernel_launch(void* const* d_in, const int* in_sizes, int n_in,
                              void* d_out, int out_size, void* d_ws, size_t ws_size,
                              hipStream_t stream) {
    const float* x  = (const float*)d_in[0];
    const int*   ei = (const int*)d_in[1];
    const float* W1 = (const float*)d_in[2];
    const float* b1 = (const float*)d_in[3];
    const float* W2 = (const float*)d_in[4];
    const float* b2 = (const float*)d_in[5];
    float* out = (float*)d_out;

    const int n_nodes = in_sizes[0] / HID;          // 10000
    const int n_edges = in_sizes[1] / 2;            // 640000

    f16* AB  = (f16*)d_ws;                          // [n_nodes, 256] f16 = 5.12 MB
    f16* W1P = AB + (long)n_nodes * TWOH;           // 64 KB
    f16* W2P = W1P + 4096 * 8;                      // 4 KB

    prep_weights<<<17, 256, 0, stream>>>(W1, W2, W1P, W2P);

    node_AB<<<((n_nodes + 15) / 16) * 4, 256, 0, stream>>>(x, W1P, b1, AB, n_nodes);

    edge_mlp<<<(n_edges + 63) / 64, 256, 0, stream>>>(AB, ei, W2P, b2, out, n_edges);
}

// Round 18
// 58.419 us; speedup vs baseline: 2.5676x; 1.6043x over previous
//
#include <hip/hip_runtime.h>

// EDeeperGCN: out[e] = relu(cat(x[src],x[dst]) @ W1 + b1) @ W2 + b2
// AB[n] = [x[n]@W1_top + b1 | x[n]@W1_bot]  (f16, in d_ws)
// out[e] = relu(A[src[e]] + B[dst[e]]) @ W2 + b2
//
// CONSOLIDATION round: edge_mlp = r11's measured-best asm ring (44.2us),
// verbatim. The edge gather wall (~8.3 TB/s CU-side request traffic, above
// the D2D copy's per-CU rate) is structural for the unsorted algorithm;
// nontemporal (r17: +50% time), sorting (r15: sort costs ~95us), bucketing
// (r14), occupancy (r13) all falsified as levers. node_AB: 32-node blocks
// + LDS-staged x-tile (kills 4x duplicate x reads and halves W1P re-reads).
// MFMA map (proven): lane=16g+r; A row r, k=32st+8g+j; B col r;
// C/D col=lane&15, row=(lane>>4)*4+reg.

typedef _Float16 f16;
typedef _Float16 f16x8 __attribute__((ext_vector_type(8)));
typedef float    f32x4 __attribute__((ext_vector_type(4)));

#define HID  128
#define TWOH 256
#define OUTD 10

// ---------------- Kernel 0: pack weight fragments ----------------
// W1P: slot = T*4 + st (T = 16-col tile of W1cat): j -> W1cat[32st+8g+j][T*16+r]
// W2P: slot = st*64 + lane: j -> W2[32st+8g+j][r] (0 if r>=10)
__global__ __launch_bounds__(256) void prep_weights(
    const float* __restrict__ W1,   // [256, 128]
    const float* __restrict__ W2,   // [128, 10]
    f16* __restrict__ W1P,          // 4096 slots x 8
    f16* __restrict__ W2P)          // 256 slots x 8
{
    const int slot = blockIdx.x * 256 + threadIdx.x;
    if (slot < 4096) {
        const int lane = slot & 63, i = slot >> 6;
        const int r = lane & 15, g = lane >> 4;
        const int T = i >> 2, st = i & 3;
        const int c = T * 16 + r;
        f16x8 v;
#pragma unroll
        for (int j = 0; j < 8; ++j) {
            const int k = st * 32 + g * 8 + j;
            const float w = (c < HID) ? W1[k * HID + c]
                                      : W1[(HID + k) * HID + (c - HID)];
            v[j] = (f16)w;
        }
        *(f16x8*)(W1P + (long)slot * 8) = v;
    } else if (slot < 4096 + 256) {
        const int s2 = slot - 4096;
        const int lane = s2 & 63, st = s2 >> 6;
        const int r = lane & 15, g = lane >> 4;
        f16x8 v;
#pragma unroll
        for (int j = 0; j < 8; ++j)
            v[j] = (r < OUTD) ? (f16)W2[(st * 32 + g * 8 + j) * OUTD + r] : (f16)0.f;
        *(f16x8*)(W2P + (long)s2 * 8) = v;
    }
}

// ---------------- Kernel 1: AB = x @ W1cat + [b1|0], f16 out, MFMA ----------------
// Block = 32 nodes x 256 cols; wave wv owns cols 64wv..+63 (T = wv*4+ct).
// x-tile (16 KB) staged once in LDS, padded [32][132] (2-way banks = free).
__global__ __launch_bounds__(256) void node_AB(
    const float* __restrict__ x,    // [N, 128]
    const f16* __restrict__ W1P,
    const float* __restrict__ b1,   // [128]
    f16* __restrict__ AB,           // [N, 256]
    int n_nodes)
{
    __shared__ float xs[32][132];
    const int t = threadIdx.x;
    const int lane = t & 63;
    const int r = lane & 15, g = lane >> 4;
    const int wv = t >> 6;
    const int n0 = blockIdx.x * 32;

    // stage 32 x-rows: 1024 f32x4, 4 per thread, coalesced
#pragma unroll
    for (int i = 0; i < 4; ++i) {
        const int idx = t + i * 256;               // f32x4 index 0..1023
        const int row = idx >> 5, c4 = idx & 31;
        const int xr = (n0 + row < n_nodes) ? (n0 + row) : (n_nodes - 1);
        *(f32x4*)&xs[row][c4 * 4] = *(const f32x4*)(x + (long)xr * HID + c4 * 4);
    }

    // weight fragments: 16 coalesced b128 loads (64 VGPR)
    f16x8 w1f[4][4];
    float bias[4];
#pragma unroll
    for (int ct = 0; ct < 4; ++ct) {
        const int T = wv * 4 + ct;
        const int c = T * 16 + r;
        bias[ct] = (c < HID) ? b1[c] : 0.f;
#pragma unroll
        for (int st = 0; st < 4; ++st)
            w1f[ct][st] = *(const f16x8*)(W1P + ((long)(T * 4 + st) * 64 + lane) * 8);
    }
    __syncthreads();

#pragma unroll
    for (int sub = 0; sub < 2; ++sub) {
        f32x4 acc[4] = {{0,0,0,0},{0,0,0,0},{0,0,0,0},{0,0,0,0}};
#pragma unroll
        for (int st = 0; st < 4; ++st) {
            const f32x4 x0 = *(const f32x4*)&xs[sub * 16 + r][st * 32 + g * 8];
            const f32x4 x1 = *(const f32x4*)&xs[sub * 16 + r][st * 32 + g * 8 + 4];
            f16x8 a;
            a[0] = (f16)x0[0]; a[1] = (f16)x0[1]; a[2] = (f16)x0[2]; a[3] = (f16)x0[3];
            a[4] = (f16)x1[0]; a[5] = (f16)x1[1]; a[6] = (f16)x1[2]; a[7] = (f16)x1[3];
#pragma unroll
            for (int ct = 0; ct < 4; ++ct)
                acc[ct] = __builtin_amdgcn_mfma_f32_16x16x32_f16(a, w1f[ct][st], acc[ct], 0, 0, 0);
        }
#pragma unroll
        for (int ct = 0; ct < 4; ++ct) {
            const int c = (wv * 4 + ct) * 16 + r;
#pragma unroll
            for (int q = 0; q < 4; ++q) {
                const int node = n0 + sub * 16 + g * 4 + q;   // D row = node
                if (node < n_nodes)
                    AB[(long)node * TWOH + c] = (f16)(acc[ct][q] + bias[ct]);
            }
        }
    }
}

// ---------------- Kernel 2: edge gather + relu + [128x10] GEMM, MFMA ----------------
// r11 verbatim (measured 44.2us): 4 waves x 128 edges, inline-asm depth-3
// gather ring, hand-counted vmcnt, LDS-staged full-line stores.
__global__ __launch_bounds__(256, 3) void edge_mlp(
    const f16* __restrict__ AB,     // [N, 256]
    const int* __restrict__ ei,     // [2, E]
    const f16* __restrict__ W2P,    // packed fragments
    const float* __restrict__ b2,   // [10]
    float* __restrict__ out,        // [E, 10]
    int n_edges)
{
    __shared__ float stage[4][160];                 // 640B per wave
    const int t = threadIdx.x;
    const int lane = t & 63;
    const int r = lane & 15, g = lane >> 4;
    const int wv = t >> 6;

    f16x8 w2f[4];
#pragma unroll
    for (int st = 0; st < 4; ++st)
        w2f[st] = *(const f16x8*)(W2P + ((long)st * 64 + lane) * 8);
    const float bj = b2[(r < OUTD) ? r : 0];

    const long eb = (long)blockIdx.x * 512 + wv * 128;

    int sn[8], dn[8];
#pragma unroll
    for (int it = 0; it < 8; ++it) {
        const long e = eb + it * 16 + r;
        const long ec = (e < n_edges) ? e : (n_edges - 1);
        sn[it] = ei[ec];
        dn[it] = ei[(long)n_edges + ec];
    }

    const f16x8 zt = {0, 0, 0, 0, 0, 0, 0, 0};

    if (eb + 128 <= n_edges) {
        asm volatile("" ::
            "v"(w2f[0]), "v"(w2f[1]), "v"(w2f[2]), "v"(w2f[3]), "v"(bj),
            "v"(sn[0]), "v"(sn[1]), "v"(sn[2]), "v"(sn[3]),
            "v"(sn[4]), "v"(sn[5]), "v"(sn[6]), "v"(sn[7]),
            "v"(dn[0]), "v"(dn[1]), "v"(dn[2]), "v"(dn[3]),
            "v"(dn[4]), "v"(dn[5]), "v"(dn[6]), "v"(dn[7]));

#define DECL(IT) f16x8 pa##IT##0, pa##IT##1, pa##IT##2, pa##IT##3, \
                       pc##IT##0, pc##IT##1, pc##IT##2, pc##IT##3;
        DECL(0) DECL(1) DECL(2) DECL(3) DECL(4) DECL(5) DECL(6) DECL(7)

#define ISSUE(IT) { \
    const f16* _pa = AB + ((long)sn[IT] * TWOH + g * 8); \
    const f16* _pb = AB + ((long)dn[IT] * TWOH + HID + g * 8); \
    asm volatile("global_load_dwordx4 %0, %1, off"            : "=v"(pa##IT##0) : "v"(_pa)); \
    asm volatile("global_load_dwordx4 %0, %1, off offset:64"  : "=v"(pa##IT##1) : "v"(_pa)); \
    asm volatile("global_load_dwordx4 %0, %1, off offset:128" : "=v"(pa##IT##2) : "v"(_pa)); \
    asm volatile("global_load_dwordx4 %0, %1, off offset:192" : "=v"(pa##IT##3) : "v"(_pa)); \
    asm volatile("global_load_dwordx4 %0, %1, off"            : "=v"(pc##IT##0) : "v"(_pb)); \
    asm volatile("global_load_dwordx4 %0, %1, off offset:64"  : "=v"(pc##IT##1) : "v"(_pb)); \
    asm volatile("global_load_dwordx4 %0, %1, off offset:128" : "=v"(pc##IT##2) : "v"(_pb)); \
    asm volatile("global_load_dwordx4 %0, %1, off offset:192" : "=v"(pc##IT##3) : "v"(_pb)); \
}

#define WAITN(IT, NSTR) \
    asm volatile("s_waitcnt vmcnt(" NSTR ")" \
        : "+v"(pa##IT##0), "+v"(pa##IT##1), "+v"(pa##IT##2), "+v"(pa##IT##3), \
          "+v"(pc##IT##0), "+v"(pc##IT##1), "+v"(pc##IT##2), "+v"(pc##IT##3)); \
    __builtin_amdgcn_sched_barrier(0);

#define COMPUTE(IT) { \
    f32x4 acc = {0, 0, 0, 0}; \
    f16x8 s; \
    s = __builtin_elementwise_max(pa##IT##0 + pc##IT##0, zt); \
    acc = __builtin_amdgcn_mfma_f32_16x16x32_f16(s, w2f[0], acc, 0, 0, 0); \
    s = __builtin_elementwise_max(pa##IT##1 + pc##IT##1, zt); \
    acc = __builtin_amdgcn_mfma_f32_16x16x32_f16(s, w2f[1], acc, 0, 0, 0); \
    s = __builtin_elementwise_max(pa##IT##2 + pc##IT##2, zt); \
    acc = __builtin_amdgcn_mfma_f32_16x16x32_f16(s, w2f[2], acc, 0, 0, 0); \
    s = __builtin_elementwise_max(pa##IT##3 + pc##IT##3, zt); \
    acc = __builtin_amdgcn_mfma_f32_16x16x32_f16(s, w2f[3], acc, 0, 0, 0); \
    if (r < OUTD) { \
        _Pragma("unroll") \
        for (int q = 0; q < 4; ++q) \
            stage[wv][(g * 4 + q) * OUTD + r] = acc[q] + bj; \
    } \
    __builtin_amdgcn_wave_barrier(); \
    if (lane < 40) { \
        const f32x4 vv = *(const f32x4*)&stage[wv][lane * 4]; \
        float* po = out + (eb + IT * 16) * OUTD + lane * 4; \
        asm volatile("global_store_dwordx4 %0, %1, off" :: "v"(po), "v"(vv) : "memory"); \
    } \
    __builtin_amdgcn_wave_barrier(); \
}

        ISSUE(0) ISSUE(1) ISSUE(2)
        WAITN(0, "16") COMPUTE(0) ISSUE(3)
        WAITN(1, "17") COMPUTE(1) ISSUE(4)
        WAITN(2, "18") COMPUTE(2) ISSUE(5)
        WAITN(3, "18") COMPUTE(3) ISSUE(6)
        WAITN(4, "18") COMPUTE(4) ISSUE(7)
        WAITN(5, "18") COMPUTE(5)
        WAITN(6, "10") COMPUTE(6)
        WAITN(7, "2")  COMPUTE(7)
        asm volatile("s_waitcnt vmcnt(0)");
#undef DECL
#undef ISSUE
#undef WAITN
#undef COMPUTE
    } else {
        // generic tail path (unused at E = 640000)
#pragma unroll
        for (int it = 0; it < 8; ++it) {
            f32x4 acc = {0, 0, 0, 0};
#pragma unroll
            for (int st = 0; st < 4; ++st) {
                const f16x8 a = *(const f16x8*)(AB + ((long)sn[it] * TWOH + st * 32 + g * 8));
                const f16x8 c = *(const f16x8*)(AB + ((long)dn[it] * TWOH + HID + st * 32 + g * 8));
                const f16x8 s = __builtin_elementwise_max(a + c, zt);
                acc = __builtin_amdgcn_mfma_f32_16x16x32_f16(s, w2f[st], acc, 0, 0, 0);
            }
            if (r < OUTD) {
#pragma unroll
                for (int q = 0; q < 4; ++q) {
                    const long ee = eb + it * 16 + g * 4 + q;
                    if (ee < n_edges) out[ee * OUTD + r] = acc[q] + bj;
                }
            }
        }
    }
}

extern "C" void kernel_launch(void* const* d_in, const int* in_sizes, int n_in,
                              void* d_out, int out_size, void* d_ws, size_t ws_size,
                              hipStream_t stream) {
    const float* x  = (const float*)d_in[0];
    const int*   ei = (const int*)d_in[1];
    const float* W1 = (const float*)d_in[2];
    const float* b1 = (const float*)d_in[3];
    const float* W2 = (const float*)d_in[4];
    const float* b2 = (const float*)d_in[5];
    float* out = (float*)d_out;

    const int n_nodes = in_sizes[0] / HID;          // 10000
    const int n_edges = in_sizes[1] / 2;            // 640000

    f16* AB  = (f16*)d_ws;                          // [n_nodes, 256] f16 = 5.12 MB
    f16* W1P = AB + (long)n_nodes * TWOH;           // 64 KB
    f16* W2P = W1P + 4096 * 8;                      // 4 KB

    prep_weights<<<17, 256, 0, stream>>>(W1, W2, W1P, W2P);

    node_AB<<<(n_nodes + 31) / 32, 256, 0, stream>>>(x, W1P, b1, AB, n_nodes);

    edge_mlp<<<(n_edges + 511) / 512, 256, 0, stream>>>(AB, ei, W2P, b2, out, n_edges);
}

// Round 19
// 58.394 us; speedup vs baseline: 2.5687x; 1.0004x over previous
//
#include <hip/hip_runtime.h>

// EDeeperGCN: out[e] = relu(cat(x[src],x[dst]) @ W1 + b1) @ W2 + b2
// AB[n] = [x[n]@W1_top + b1 | x[n]@W1_bot]  (f16, in d_ws)
// out[e] = relu(A[src[e]] + B[dst[e]]) @ W2 + b2
//
// edge_mlp = r11's measured-best asm ring (44.2us), verbatim: the edge
// gather wall (327.7 MB line-perfect L2->CU traffic at ~12-13 B/cyc/CU)
// is the per-CU VMEM return-path roofline; occupancy (r13), bucketing (r14),
// sorting (r15), nontemporal (r17) all falsified as levers, fp8 ruled out
// by error arithmetic (max-err ~0.26 > 0.0725 threshold).
// node_AB: 32 nodes x 128 cols per block (626 blocks, 2.4/CU) -- same total
// weight/x traffic as the 313-block version, half the exposed latency.
// MFMA map (proven): lane=16g+r; A row r, k=32st+8g+j; B col r;
// C/D col=lane&15, row=(lane>>4)*4+reg.

typedef _Float16 f16;
typedef _Float16 f16x8 __attribute__((ext_vector_type(8)));
typedef float    f32x4 __attribute__((ext_vector_type(4)));

#define HID  128
#define TWOH 256
#define OUTD 10

// ---------------- Kernel 0: pack weight fragments ----------------
// W1P: slot = T*4 + st (T = 16-col tile of W1cat): j -> W1cat[32st+8g+j][T*16+r]
// W2P: slot = st*64 + lane: j -> W2[32st+8g+j][r] (0 if r>=10)
__global__ __launch_bounds__(256) void prep_weights(
    const float* __restrict__ W1,   // [256, 128]
    const float* __restrict__ W2,   // [128, 10]
    f16* __restrict__ W1P,          // 4096 slots x 8
    f16* __restrict__ W2P)          // 256 slots x 8
{
    const int slot = blockIdx.x * 256 + threadIdx.x;
    if (slot < 4096) {
        const int lane = slot & 63, i = slot >> 6;
        const int r = lane & 15, g = lane >> 4;
        const int T = i >> 2, st = i & 3;
        const int c = T * 16 + r;
        f16x8 v;
#pragma unroll
        for (int j = 0; j < 8; ++j) {
            const int k = st * 32 + g * 8 + j;
            const float w = (c < HID) ? W1[k * HID + c]
                                      : W1[(HID + k) * HID + (c - HID)];
            v[j] = (f16)w;
        }
        *(f16x8*)(W1P + (long)slot * 8) = v;
    } else if (slot < 4096 + 256) {
        const int s2 = slot - 4096;
        const int lane = s2 & 63, st = s2 >> 6;
        const int r = lane & 15, g = lane >> 4;
        f16x8 v;
#pragma unroll
        for (int j = 0; j < 8; ++j)
            v[j] = (r < OUTD) ? (f16)W2[(st * 32 + g * 8 + j) * OUTD + r] : (f16)0.f;
        *(f16x8*)(W2P + (long)s2 * 8) = v;
    }
}

// ---------------- Kernel 1: AB = x @ W1cat + [b1|0], f16 out, MFMA ----------------
// Block b: node tile b>>1 (32 nodes), column half b&1 (128 cols).
// Wave owns 2 16-col tiles: T = (b&1)*8 + wv*2 + ct.
// x-tile (16 KB) staged once in LDS, padded [32][132] (2-way banks = free).
__global__ __launch_bounds__(256) void node_AB(
    const float* __restrict__ x,    // [N, 128]
    const f16* __restrict__ W1P,
    const float* __restrict__ b1,   // [128]
    f16* __restrict__ AB,           // [N, 256]
    int n_nodes)
{
    __shared__ float xs[32][132];
    const int t = threadIdx.x;
    const int lane = t & 63;
    const int r = lane & 15, g = lane >> 4;
    const int wv = t >> 6;
    const int n0 = (blockIdx.x >> 1) * 32;
    const int ch = blockIdx.x & 1;

    // stage 32 x-rows: 1024 f32x4, 4 per thread, coalesced
#pragma unroll
    for (int i = 0; i < 4; ++i) {
        const int idx = t + i * 256;               // f32x4 index 0..1023
        const int row = idx >> 5, c4 = idx & 31;
        const int xr = (n0 + row < n_nodes) ? (n0 + row) : (n_nodes - 1);
        *(f32x4*)&xs[row][c4 * 4] = *(const f32x4*)(x + (long)xr * HID + c4 * 4);
    }

    // weight fragments: 8 coalesced b128 loads (32 VGPR)
    f16x8 w1f[2][4];
    float bias[2];
#pragma unroll
    for (int ct = 0; ct < 2; ++ct) {
        const int T = ch * 8 + wv * 2 + ct;
        const int c = T * 16 + r;
        bias[ct] = (c < HID) ? b1[c] : 0.f;
#pragma unroll
        for (int st = 0; st < 4; ++st)
            w1f[ct][st] = *(const f16x8*)(W1P + ((long)(T * 4 + st) * 64 + lane) * 8);
    }
    __syncthreads();

#pragma unroll
    for (int sub = 0; sub < 2; ++sub) {
        f32x4 acc[2] = {{0,0,0,0},{0,0,0,0}};
#pragma unroll
        for (int st = 0; st < 4; ++st) {
            const f32x4 x0 = *(const f32x4*)&xs[sub * 16 + r][st * 32 + g * 8];
            const f32x4 x1 = *(const f32x4*)&xs[sub * 16 + r][st * 32 + g * 8 + 4];
            f16x8 a;
            a[0] = (f16)x0[0]; a[1] = (f16)x0[1]; a[2] = (f16)x0[2]; a[3] = (f16)x0[3];
            a[4] = (f16)x1[0]; a[5] = (f16)x1[1]; a[6] = (f16)x1[2]; a[7] = (f16)x1[3];
#pragma unroll
            for (int ct = 0; ct < 2; ++ct)
                acc[ct] = __builtin_amdgcn_mfma_f32_16x16x32_f16(a, w1f[ct][st], acc[ct], 0, 0, 0);
        }
#pragma unroll
        for (int ct = 0; ct < 2; ++ct) {
            const int c = (ch * 8 + wv * 2 + ct) * 16 + r;
#pragma unroll
            for (int q = 0; q < 4; ++q) {
                const int node = n0 + sub * 16 + g * 4 + q;   // D row = node
                if (node < n_nodes)
                    AB[(long)node * TWOH + c] = (f16)(acc[ct][q] + bias[ct]);
            }
        }
    }
}

// ---------------- Kernel 2: edge gather + relu + [128x10] GEMM, MFMA ----------------
// r11 verbatim (measured 44.2us): 4 waves x 128 edges, inline-asm depth-3
// gather ring, hand-counted vmcnt, LDS-staged full-line stores.
__global__ __launch_bounds__(256, 3) void edge_mlp(
    const f16* __restrict__ AB,     // [N, 256]
    const int* __restrict__ ei,     // [2, E]
    const f16* __restrict__ W2P,    // packed fragments
    const float* __restrict__ b2,   // [10]
    float* __restrict__ out,        // [E, 10]
    int n_edges)
{
    __shared__ float stage[4][160];                 // 640B per wave
    const int t = threadIdx.x;
    const int lane = t & 63;
    const int r = lane & 15, g = lane >> 4;
    const int wv = t >> 6;

    f16x8 w2f[4];
#pragma unroll
    for (int st = 0; st < 4; ++st)
        w2f[st] = *(const f16x8*)(W2P + ((long)st * 64 + lane) * 8);
    const float bj = b2[(r < OUTD) ? r : 0];

    const long eb = (long)blockIdx.x * 512 + wv * 128;

    int sn[8], dn[8];
#pragma unroll
    for (int it = 0; it < 8; ++it) {
        const long e = eb + it * 16 + r;
        const long ec = (e < n_edges) ? e : (n_edges - 1);
        sn[it] = ei[ec];
        dn[it] = ei[(long)n_edges + ec];
    }

    const f16x8 zt = {0, 0, 0, 0, 0, 0, 0, 0};

    if (eb + 128 <= n_edges) {
        asm volatile("" ::
            "v"(w2f[0]), "v"(w2f[1]), "v"(w2f[2]), "v"(w2f[3]), "v"(bj),
            "v"(sn[0]), "v"(sn[1]), "v"(sn[2]), "v"(sn[3]),
            "v"(sn[4]), "v"(sn[5]), "v"(sn[6]), "v"(sn[7]),
            "v"(dn[0]), "v"(dn[1]), "v"(dn[2]), "v"(dn[3]),
            "v"(dn[4]), "v"(dn[5]), "v"(dn[6]), "v"(dn[7]));

#define DECL(IT) f16x8 pa##IT##0, pa##IT##1, pa##IT##2, pa##IT##3, \
                       pc##IT##0, pc##IT##1, pc##IT##2, pc##IT##3;
        DECL(0) DECL(1) DECL(2) DECL(3) DECL(4) DECL(5) DECL(6) DECL(7)

#define ISSUE(IT) { \
    const f16* _pa = AB + ((long)sn[IT] * TWOH + g * 8); \
    const f16* _pb = AB + ((long)dn[IT] * TWOH + HID + g * 8); \
    asm volatile("global_load_dwordx4 %0, %1, off"            : "=v"(pa##IT##0) : "v"(_pa)); \
    asm volatile("global_load_dwordx4 %0, %1, off offset:64"  : "=v"(pa##IT##1) : "v"(_pa)); \
    asm volatile("global_load_dwordx4 %0, %1, off offset:128" : "=v"(pa##IT##2) : "v"(_pa)); \
    asm volatile("global_load_dwordx4 %0, %1, off offset:192" : "=v"(pa##IT##3) : "v"(_pa)); \
    asm volatile("global_load_dwordx4 %0, %1, off"            : "=v"(pc##IT##0) : "v"(_pb)); \
    asm volatile("global_load_dwordx4 %0, %1, off offset:64"  : "=v"(pc##IT##1) : "v"(_pb)); \
    asm volatile("global_load_dwordx4 %0, %1, off offset:128" : "=v"(pc##IT##2) : "v"(_pb)); \
    asm volatile("global_load_dwordx4 %0, %1, off offset:192" : "=v"(pc##IT##3) : "v"(_pb)); \
}

#define WAITN(IT, NSTR) \
    asm volatile("s_waitcnt vmcnt(" NSTR ")" \
        : "+v"(pa##IT##0), "+v"(pa##IT##1), "+v"(pa##IT##2), "+v"(pa##IT##3), \
          "+v"(pc##IT##0), "+v"(pc##IT##1), "+v"(pc##IT##2), "+v"(pc##IT##3)); \
    __builtin_amdgcn_sched_barrier(0);

#define COMPUTE(IT) { \
    f32x4 acc = {0, 0, 0, 0}; \
    f16x8 s; \
    s = __builtin_elementwise_max(pa##IT##0 + pc##IT##0, zt); \
    acc = __builtin_amdgcn_mfma_f32_16x16x32_f16(s, w2f[0], acc, 0, 0, 0); \
    s = __builtin_elementwise_max(pa##IT##1 + pc##IT##1, zt); \
    acc = __builtin_amdgcn_mfma_f32_16x16x32_f16(s, w2f[1], acc, 0, 0, 0); \
    s = __builtin_elementwise_max(pa##IT##2 + pc##IT##2, zt); \
    acc = __builtin_amdgcn_mfma_f32_16x16x32_f16(s, w2f[2], acc, 0, 0, 0); \
    s = __builtin_elementwise_max(pa##IT##3 + pc##IT##3, zt); \
    acc = __builtin_amdgcn_mfma_f32_16x16x32_f16(s, w2f[3], acc, 0, 0, 0); \
    if (r < OUTD) { \
        _Pragma("unroll") \
        for (int q = 0; q < 4; ++q) \
            stage[wv][(g * 4 + q) * OUTD + r] = acc[q] + bj; \
    } \
    __builtin_amdgcn_wave_barrier(); \
    if (lane < 40) { \
        const f32x4 vv = *(const f32x4*)&stage[wv][lane * 4]; \
        float* po = out + (eb + IT * 16) * OUTD + lane * 4; \
        asm volatile("global_store_dwordx4 %0, %1, off" :: "v"(po), "v"(vv) : "memory"); \
    } \
    __builtin_amdgcn_wave_barrier(); \
}

        ISSUE(0) ISSUE(1) ISSUE(2)
        WAITN(0, "16") COMPUTE(0) ISSUE(3)
        WAITN(1, "17") COMPUTE(1) ISSUE(4)
        WAITN(2, "18") COMPUTE(2) ISSUE(5)
        WAITN(3, "18") COMPUTE(3) ISSUE(6)
        WAITN(4, "18") COMPUTE(4) ISSUE(7)
        WAITN(5, "18") COMPUTE(5)
        WAITN(6, "10") COMPUTE(6)
        WAITN(7, "2")  COMPUTE(7)
        asm volatile("s_waitcnt vmcnt(0)");
#undef DECL
#undef ISSUE
#undef WAITN
#undef COMPUTE
    } else {
        // generic tail path (unused at E = 640000)
#pragma unroll
        for (int it = 0; it < 8; ++it) {
            f32x4 acc = {0, 0, 0, 0};
#pragma unroll
            for (int st = 0; st < 4; ++st) {
                const f16x8 a = *(const f16x8*)(AB + ((long)sn[it] * TWOH + st * 32 + g * 8));
                const f16x8 c = *(const f16x8*)(AB + ((long)dn[it] * TWOH + HID + st * 32 + g * 8));
                const f16x8 s = __builtin_elementwise_max(a + c, zt);
                acc = __builtin_amdgcn_mfma_f32_16x16x32_f16(s, w2f[st], acc, 0, 0, 0);
            }
            if (r < OUTD) {
#pragma unroll
                for (int q = 0; q < 4; ++q) {
                    const long ee = eb + it * 16 + g * 4 + q;
                    if (ee < n_edges) out[ee * OUTD + r] = acc[q] + bj;
                }
            }
        }
    }
}

extern "C" void kernel_launch(void* const* d_in, const int* in_sizes, int n_in,
                              void* d_out, int out_size, void* d_ws, size_t ws_size,
                              hipStream_t stream) {
    const float* x  = (const float*)d_in[0];
    const int*   ei = (const int*)d_in[1];
    const float* W1 = (const float*)d_in[2];
    const float* b1 = (const float*)d_in[3];
    const float* W2 = (const float*)d_in[4];
    const float* b2 = (const float*)d_in[5];
    float* out = (float*)d_out;

    const int n_nodes = in_sizes[0] / HID;          // 10000
    const int n_edges = in_sizes[1] / 2;            // 640000

    f16* AB  = (f16*)d_ws;                          // [n_nodes, 256] f16 = 5.12 MB
    f16* W1P = AB + (long)n_nodes * TWOH;           // 64 KB
    f16* W2P = W1P + 4096 * 8;                      // 4 KB

    prep_weights<<<17, 256, 0, stream>>>(W1, W2, W1P, W2P);

    node_AB<<<((n_nodes + 31) / 32) * 2, 256, 0, stream>>>(x, W1P, b1, AB, n_nodes);

    edge_mlp<<<(n_edges + 511) / 512, 256, 0, stream>>>(AB, ei, W2P, b2, out, n_edges);
}